// Round 7
// baseline (29.932 us; speedup 1.0000x reference)
//
#include <hip/hip_runtime.h>
#include <hip/hip_bf16.h>
#include <math.h>

#define BS 128
#define NQ 300
#define NT 16
#define CPL 5   // columns per lane: 300 = 60 lanes * 5 cols (Dijkstra/ARR mapping)

union DI { double d; int i[2]; };

// f64 value-only min reduce step via DPP (VALU latency, no index carry)
#define DPP_MIN_STEP(CTRL)                                                    \
    {                                                                         \
        DI a_; a_.d = bestv;                                                  \
        DI p_;                                                                \
        p_.i[0] = __builtin_amdgcn_update_dpp(a_.i[0], a_.i[0], CTRL, 0xF, 0xF, false); \
        p_.i[1] = __builtin_amdgcn_update_dpp(a_.i[1], a_.i[1], CTRL, 0xF, 0xF, false); \
        bestv = fmin(bestv, p_.d);                                            \
    }
#define DPP_MIN_ALL  DPP_MIN_STEP(0x111) DPP_MIN_STEP(0x112) DPP_MIN_STEP(0x114) \
                     DPP_MIN_STEP(0x118) DPP_MIN_STEP(0x142) DPP_MIN_STEP(0x143)

// f32 value-only min reduce step via DPP (operates on local var `rv`)
#define DPP_MINF_STEP(CTRL)                                                   \
    {                                                                         \
        int p_ = __builtin_amdgcn_update_dpp(__float_as_int(rv), __float_as_int(rv), CTRL, 0xF, 0xF, false); \
        rv = fminf(rv, __int_as_float(p_));                                   \
    }
#define DPP_MINF_ALL DPP_MINF_STEP(0x111) DPP_MINF_STEP(0x112) DPP_MINF_STEP(0x114) \
                     DPP_MINF_STEP(0x118) DPP_MINF_STEP(0x142) DPP_MINF_STEP(0x143)

__device__ __forceinline__ double readlane_d(double x, int lane) {
    DI a; a.d = x;
    DI r;
    r.i[0] = __builtin_amdgcn_readlane(a.i[0], lane);
    r.i[1] = __builtin_amdgcn_readlane(a.i[1], lane);
    return r.d;
}

__device__ __forceinline__ int sel5(const int* a, int slot) {
    int r = a[0];
    r = (slot == 1) ? a[1] : r;
    r = (slot == 2) ? a[2] : r;
    r = (slot == 3) ? a[3] : r;
    r = (slot == 4) ? a[4] : r;
    return r;
}

// ---------------------------------------------------------------------------
// Fused kernel: per-batch cost-matrix compute (+ C store, bit-identical
// expression to the validated cost_kernel) + JV assignment:
//   row-min init -> greedy tight assignment -> ARR for conflicts ->
//   exact f64 Dijkstra for leftovers. One wave (64 lanes) per batch.
// Final matching is optimal; optimum unique on this data => equals the
// numpy reference output.
// ---------------------------------------------------------------------------
__global__ __launch_bounds__(64) void lsa_fused(const float* __restrict__ pred_boxes, // [BS,NQ,4]
                                                const float* __restrict__ logits_b,   // [BS,NQ,2]
                                                const float* __restrict__ tgt_boxes,  // [BS,NT,5]
                                                float* __restrict__ C,                // [BS,NQ,NT]
                                                float* __restrict__ rows_out,         // [BS,NT]
                                                float* __restrict__ cols_out)         // [BS,NT]
{
    const int b    = blockIdx.x;
    const int lane = threadIdx.x;

    __shared__ float  cost[NT][NQ];          // cost[t][q]
    __shared__ double u_add[NT];
    __shared__ __align__(16) float tgt_s[NT][4];

    // stage targets: 64 lanes cover 16*4 floats exactly
    {
        int t = lane >> 2, d = lane & 3;
        tgt_s[t][d] = tgt_boxes[((size_t)b * NT + t) * 5 + 1 + d];
    }
    if (lane < NT) u_add[lane] = 0.0;
    __syncthreads();

    const bool has_cols   = (lane < 60);
    const int  cbase      = has_cols ? lane * CPL : 0;
    const unsigned valid0 = has_cols ? 0x1Fu : 0u;

    // ---- fused cost compute + C store + per-lane row-min tracking ----
    float rmin[NT]; int rarg[NT];
    #pragma unroll
    for (int t = 0; t < NT; ++t) { rmin[t] = 1e30f; rarg[t] = 0; }

    float* Cb = C + (size_t)b * NQ * NT;
    #pragma unroll
    for (int jj = 0; jj < 5; ++jj) {
        int q = lane + 64 * jj;
        bool has = (q < NQ);
        float4 pb = make_float4(0.f, 0.f, 0.f, 0.f);
        float2 lg = make_float2(0.f, 0.f);
        if (has) {
            pb = *reinterpret_cast<const float4*>(pred_boxes + ((size_t)b * NQ + q) * 4);
            lg = *reinterpret_cast<const float2*>(logits_b  + ((size_t)b * NQ + q) * 2);
        }
        float pcx = pb.x, pcy = pb.y, pw = pb.z, ph = pb.w;
        // softmax prob of class 1 (same expression as validated kernel)
        float mm = fmaxf(lg.x, lg.y);
        float e0 = expf(lg.x - mm), e1 = expf(lg.y - mm);
        float p1 = e1 / (e0 + e1);
        float ax1 = pcx - 0.5f * pw, ay1 = pcy - 0.5f * ph;
        float ax2 = pcx + 0.5f * pw, ay2 = pcy + 0.5f * ph;
        float area_a = (ax2 - ax1) * (ay2 - ay1);

        float cv[NT];
        #pragma unroll
        for (int t = 0; t < NT; ++t) {
            float tcx = tgt_s[t][0], tcy = tgt_s[t][1], tw = tgt_s[t][2], th = tgt_s[t][3];
            float cost_bbox = fabsf(pcx - tcx) + fabsf(pcy - tcy) + fabsf(pw - tw) + fabsf(ph - th);
            float bx1 = tcx - 0.5f * tw, by1 = tcy - 0.5f * th;
            float bx2 = tcx + 0.5f * tw, by2 = tcy + 0.5f * th;
            float area_b = (bx2 - bx1) * (by2 - by1);
            float ltx = fmaxf(ax1, bx1), lty = fmaxf(ay1, by1);
            float rbx = fminf(ax2, bx2), rby = fminf(ay2, by2);
            float wx = fmaxf(rbx - ltx, 0.0f), wy = fmaxf(rby - lty, 0.0f);
            float inter = wx * wy;
            float uni = area_a + area_b - inter;
            float iou = inter / uni;
            float ex1 = fminf(ax1, bx1), ey1 = fminf(ay1, by1);
            float ex2 = fmaxf(ax2, bx2), ey2 = fmaxf(ay2, by2);
            float ewx = fmaxf(ex2 - ex1, 0.0f), ewy = fmaxf(ey2 - ey1, 0.0f);
            float area_e = ewx * ewy;
            float giou = iou - (area_e - uni) / area_e;
            float ct = 5.0f * cost_bbox - 2.0f * giou - p1;
            cv[t] = ct;
            if (has) {
                cost[t][q] = ct;
                if (ct < rmin[t]) { rmin[t] = ct; rarg[t] = q; }  // ascending q per lane
            }
        }
        if (has) {
            float4* dst = reinterpret_cast<float4*>(Cb + (size_t)q * NT);
            dst[0] = make_float4(cv[0],  cv[1],  cv[2],  cv[3]);
            dst[1] = make_float4(cv[4],  cv[5],  cv[6],  cv[7]);
            dst[2] = make_float4(cv[8],  cv[9],  cv[10], cv[11]);
            dst[3] = make_float4(cv[12], cv[13], cv[14], cv[15]);
        }
    }
    __syncthreads();

    // ---- dual / assignment state (registers) ----
    double v_reg[CPL];
    int    r4c_reg[CPL];
    int    path_reg[CPL];
    #pragma unroll
    for (int j = 0; j < CPL; ++j) { v_reg[j] = 0.0; r4c_reg[j] = -1; path_reg[j] = -1; }
    double u_reg   = 0.0;     // u[lane] on lanes 0..15
    int    c4r_reg = -1;      // col4row[lane] on lanes 0..15

    // ---- row-min reduces: u[i] = min_q cost[i][q], jstar[i] = argmin ----
    int jstar[NT];
    #pragma unroll
    for (int i = 0; i < NT; ++i) {
        float rv = rmin[i];
        DPP_MINF_ALL
        float m = __int_as_float(__builtin_amdgcn_readlane(__float_as_int(rv), 63));
        unsigned long long tied = __ballot(rmin[i] == m);
        int l = __ffsll(tied) - 1;
        jstar[i] = __builtin_amdgcn_readlane(rarg[i], l);
        if (lane == i) u_reg = (double)m;   // exact: f32 min == f64 min of casts
    }

    // ---- greedy assignment on tight edges ----
    unsigned unassigned = 0;
    #pragma unroll
    for (int i = 0; i < NT; ++i) {
        int k = jstar[i];
        int owner = k / CPL;
        int slot  = k - owner * CPL;
        int rk    = __builtin_amdgcn_readlane(sel5(r4c_reg, slot), owner);
        if (rk == -1) {
            bool me = (lane == owner);
            r4c_reg[0] = (me && slot == 0) ? i : r4c_reg[0];
            r4c_reg[1] = (me && slot == 1) ? i : r4c_reg[1];
            r4c_reg[2] = (me && slot == 2) ? i : r4c_reg[2];
            r4c_reg[3] = (me && slot == 3) ? i : r4c_reg[3];
            r4c_reg[4] = (me && slot == 4) ? i : r4c_reg[4];
            c4r_reg    = (lane == i) ? k : c4r_reg;
        } else {
            unassigned |= (1u << i);
        }
    }

    // ---- ARR (JV augmenting row reduction) for conflicted rows ----
    // Invariants kept: r(i,j)=c-u[i]-v[j] >= 0 for all; assigned pairs tight.
    {
        unsigned queue = unassigned;
        int steps = 0;
        while (queue && steps < 64) {
            ++steps;
            int i = __ffs(queue) - 1;           // uniform
            queue &= ~(1u << i);

            const float* crow = &cost[0][0] + i * NQ + cbase;
            double rc[CPL];
            double bv = 1e300; int bj = 0;
            #pragma unroll
            for (int j = 0; j < CPL; ++j) {
                rc[j] = (valid0 & (1u << j)) ? ((double)crow[j] - v_reg[j]) : 1e300;
                if (rc[j] < bv) { bv = rc[j]; bj = j; }
            }
            double bestv = bv;
            DPP_MIN_ALL
            double v1 = readlane_d(bestv, 63);
            unsigned long long tied = __ballot(bv == v1);
            if (tied == 0ull) break;            // NaN guard
            int l  = __ffsll(tied) - 1;         // owner lane of j1
            int j1 = __builtin_amdgcn_readlane(cbase + bj, l);
            int slot = j1 - l * CPL;            // uniform

            // second min excluding column j1
            double bv2 = 1e300;
            #pragma unroll
            for (int j = 0; j < CPL; ++j) {
                double x = rc[j];
                if (lane == l && j == slot) x = 1e300;
                if (x < bv2) bv2 = x;
            }
            bestv = bv2;
            DPP_MIN_ALL
            double v2 = readlane_d(bestv, 63);

            // duals: u[i] = v2; if v1 < v2: v[j1] -= (v2 - v1)
            if (lane == i) u_reg = v2;
            double dd = v2 - v1;
            if (lane == l && dd > 0.0) {
                v_reg[0] = (slot == 0) ? v_reg[0] - dd : v_reg[0];
                v_reg[1] = (slot == 1) ? v_reg[1] - dd : v_reg[1];
                v_reg[2] = (slot == 2) ? v_reg[2] - dd : v_reg[2];
                v_reg[3] = (slot == 3) ? v_reg[3] - dd : v_reg[3];
                v_reg[4] = (slot == 4) ? v_reg[4] - dd : v_reg[4];
            }

            // displace owner of j1 (if any), assign i -> j1
            int rk = __builtin_amdgcn_readlane(sel5(r4c_reg, slot), l);
            bool me = (lane == l);
            r4c_reg[0] = (me && slot == 0) ? i : r4c_reg[0];
            r4c_reg[1] = (me && slot == 1) ? i : r4c_reg[1];
            r4c_reg[2] = (me && slot == 2) ? i : r4c_reg[2];
            r4c_reg[3] = (me && slot == 3) ? i : r4c_reg[3];
            r4c_reg[4] = (me && slot == 4) ? i : r4c_reg[4];
            c4r_reg = (lane == i) ? j1 : c4r_reg;
            if (rk != -1) {
                c4r_reg = (lane == rk) ? -1 : c4r_reg;
                queue |= (1u << rk);
            }
        }
        unassigned = queue;   // leftovers -> exact Dijkstra
    }

    // ---- exact f64 Dijkstra augmentation for leftover rows ----
    for (int cur_row = 0; cur_row < NT; ++cur_row) {
        if (!((unassigned >> cur_row) & 1u)) continue;

        double minv_reg[CPL];
        #pragma unroll
        for (int j = 0; j < CPL; ++j) { minv_reg[j] = 1e300; path_reg[j] = -1; }
        unsigned rem = valid0;

        double shortest = 0.0;
        int i = cur_row;
        int sink = -1;

        for (int guard = 0; guard <= NT && sink < 0; ++guard) {
            const double ui = readlane_d(u_reg, i);

            const float* crow = &cost[0][0] + i * NQ + cbase;
            float cf[CPL];
            #pragma unroll
            for (int j = 0; j < CPL; ++j) cf[j] = crow[j];

            double bestv = 1e300;
            int    bj    = 0;
            #pragma unroll
            for (int j = 0; j < CPL; ++j) {
                unsigned bit = 1u << j;
                if (rem & bit) {
                    double r = ((shortest + (double)cf[j]) - ui) - v_reg[j];
                    if (r < minv_reg[j]) { minv_reg[j] = r; path_reg[j] = i; }
                }
                double cv = (rem & bit) ? minv_reg[j] : 1e300;
                if (cv < bestv) { bestv = cv; bj = j; }
            }
            int bestc = cbase + bj;

            DPP_MIN_ALL

            const double m = readlane_d(bestv, 63);
            unsigned long long tied = __ballot(bestv == m);
            if (tied == 0ull) break;            // NaN guard
            int l = __ffsll(tied) - 1;
            int k = __builtin_amdgcn_readlane(bestc, l);
            shortest = m;

            int owner = k / CPL;
            int slot  = k - owner * CPL;
            if (lane == owner) rem &= ~(1u << slot);

            int rk = __builtin_amdgcn_readlane(sel5(r4c_reg, slot), owner);
            if (rk == -1) sink = k;
            else          i = rk;
        }

        // dual updates for scanned (= popped) columns
        #pragma unroll
        for (int j = 0; j < CPL; ++j) {
            unsigned bit = 1u << j;
            if ((valid0 & bit) && !(rem & bit)) {
                double d = shortest - minv_reg[j];
                int r = r4c_reg[j];
                if (r != -1) u_add[r] = d;
                v_reg[j] -= d;
            }
        }
        __syncthreads();
        if (lane == cur_row) u_reg += shortest;
        if (lane < NT) { u_reg += u_add[lane]; u_add[lane] = 0.0; }
        __syncthreads();

        // augment along path (uniform scalar walk on registers)
        if (sink >= 0) {
            int j = sink;
            #pragma unroll 1
            for (int it = 0; it <= NT; ++it) {
                int ow = j / CPL;
                int sl = j - ow * CPL;
                int ii = __builtin_amdgcn_readlane(sel5(path_reg, sl), ow);
                bool me = (lane == ow);
                r4c_reg[0] = (me && sl == 0) ? ii : r4c_reg[0];
                r4c_reg[1] = (me && sl == 1) ? ii : r4c_reg[1];
                r4c_reg[2] = (me && sl == 2) ? ii : r4c_reg[2];
                r4c_reg[3] = (me && sl == 3) ? ii : r4c_reg[3];
                r4c_reg[4] = (me && sl == 4) ? ii : r4c_reg[4];
                int tmp = __builtin_amdgcn_readlane(c4r_reg, ii);
                c4r_reg = (lane == ii) ? j : c4r_reg;
                j = tmp;
                if (ii == cur_row) break;
            }
        }
    }

    // ---- outputs: order = argsort(col4row) via rank (values distinct) ----
    int myval = c4r_reg;
    int rank = 0;
    #pragma unroll
    for (int s = 0; s < NT; ++s) {
        int vs = __builtin_amdgcn_readlane(c4r_reg, s);
        rank += (vs < myval) ? 1 : 0;
    }
    if (lane < NT) {
        rows_out[b * NT + rank] = (float)myval;
        cols_out[b * NT + rank] = (float)lane;
    }
}

extern "C" void kernel_launch(void* const* d_in, const int* in_sizes, int n_in,
                              void* d_out, int out_size, void* d_ws, size_t ws_size,
                              hipStream_t stream) {
    const float* pred_boxes = (const float*)d_in[1];
    const float* logits_b   = (const float*)d_in[2];
    const float* tgt_boxes  = (const float*)d_in[3];

    float* C    = (float*)d_out;                   // [BS,NQ,NT]
    float* rows = C + (size_t)BS * NQ * NT;        // [BS,NT]
    float* cols = rows + (size_t)BS * NT;          // [BS,NT]

    lsa_fused<<<BS, 64, 0, stream>>>(pred_boxes, logits_b, tgt_boxes, C, rows, cols);
}

// Round 10
// 29.745 us; speedup vs baseline: 1.0063x; 1.0063x over previous
//
#include <hip/hip_runtime.h>
#include <hip/hip_bf16.h>
#include <math.h>

#define BS 128
#define NQ 300
#define NT 16
#define CPL 5   // columns per lane: 300 = 60 lanes * 5 cols, lanes 60..63 idle

union DI { double d; int i[2]; };

// f64 value-only min reduce step via DPP (VALU latency, no index carry)
#define DPP_MIN_STEP(CTRL)                                                    \
    {                                                                         \
        DI a_; a_.d = bestv;                                                  \
        DI p_;                                                                \
        p_.i[0] = __builtin_amdgcn_update_dpp(a_.i[0], a_.i[0], CTRL, 0xF, 0xF, false); \
        p_.i[1] = __builtin_amdgcn_update_dpp(a_.i[1], a_.i[1], CTRL, 0xF, 0xF, false); \
        bestv = fmin(bestv, p_.d);                                            \
    }
#define DPP_MIN_ALL  DPP_MIN_STEP(0x111) DPP_MIN_STEP(0x112) DPP_MIN_STEP(0x114) \
                     DPP_MIN_STEP(0x118) DPP_MIN_STEP(0x142) DPP_MIN_STEP(0x143)

// f32 value-only min reduce step via DPP (operates on local var `rv`)
#define DPP_MINF_STEP(CTRL)                                                   \
    {                                                                         \
        int p_ = __builtin_amdgcn_update_dpp(__float_as_int(rv), __float_as_int(rv), CTRL, 0xF, 0xF, false); \
        rv = fminf(rv, __int_as_float(p_));                                   \
    }
#define DPP_MINF_ALL DPP_MINF_STEP(0x111) DPP_MINF_STEP(0x112) DPP_MINF_STEP(0x114) \
                     DPP_MINF_STEP(0x118) DPP_MINF_STEP(0x142) DPP_MINF_STEP(0x143)

__device__ __forceinline__ double readlane_d(double x, int lane) {
    DI a; a.d = x;
    DI r;
    r.i[0] = __builtin_amdgcn_readlane(a.i[0], lane);
    r.i[1] = __builtin_amdgcn_readlane(a.i[1], lane);
    return r.d;
}

__device__ __forceinline__ int sel5(const int* a, int slot) {
    int r = a[0];
    r = (slot == 1) ? a[1] : r;
    r = (slot == 2) ? a[2] : r;
    r = (slot == 3) ? a[3] : r;
    r = (slot == 4) ? a[4] : r;
    return r;
}

// ---------------------------------------------------------------------------
// Fused kernel: per-batch cost compute (identical f32 expression to the
// validated cost_kernel; C stored bit-identical) + R6's PROVEN assignment:
//   rowmin greedy (v = 0 duals, numpy first-min tie-breaks) ->
//   exact f64 Dijkstra fallback (reference evaluation order).
// No column reduction, no ARR (R8/R9 showed any colmin-based dual init
// lands on a different optimal matching in a tied batch).
// One wave per batch; single-wave block => no __syncthreads needed inside
// the assignment loops (intra-wave LDS deps ordered by lgkmcnt).
// ---------------------------------------------------------------------------
__global__ __launch_bounds__(64) void lsa_fused(const float* __restrict__ pred_boxes, // [BS,NQ,4]
                                                const float* __restrict__ logits_b,   // [BS,NQ,2]
                                                const float* __restrict__ tgt_boxes,  // [BS,NT,5]
                                                float* __restrict__ C,                // [BS,NQ,NT]
                                                float* __restrict__ rows_out,         // [BS,NT]
                                                float* __restrict__ cols_out)         // [BS,NT]
{
    const int b    = blockIdx.x;
    const int lane = threadIdx.x;

    __shared__ float  cost[NT][NQ];          // cost[t][q]
    __shared__ double u_add[NT];
    __shared__ __align__(16) float tgt_s[NT][4];

    // stage targets: 64 lanes cover 16*4 floats exactly
    {
        int t = lane >> 2, d = lane & 3;
        tgt_s[t][d] = tgt_boxes[((size_t)b * NT + t) * 5 + 1 + d];
    }
    if (lane < NT) u_add[lane] = 0.0;
    __syncthreads();

    // ---- fused cost compute + C store + LDS tile (validated in R7) ----
    float* Cb = C + (size_t)b * NQ * NT;
    #pragma unroll
    for (int jj = 0; jj < 5; ++jj) {
        int q = lane + 64 * jj;
        bool has = (q < NQ);
        float4 pb = make_float4(0.f, 0.f, 0.f, 0.f);
        float2 lg = make_float2(0.f, 0.f);
        if (has) {
            pb = *reinterpret_cast<const float4*>(pred_boxes + ((size_t)b * NQ + q) * 4);
            lg = *reinterpret_cast<const float2*>(logits_b  + ((size_t)b * NQ + q) * 2);
        }
        float pcx = pb.x, pcy = pb.y, pw = pb.z, ph = pb.w;
        float mm = fmaxf(lg.x, lg.y);
        float e0 = expf(lg.x - mm), e1 = expf(lg.y - mm);
        float p1 = e1 / (e0 + e1);
        float ax1 = pcx - 0.5f * pw, ay1 = pcy - 0.5f * ph;
        float ax2 = pcx + 0.5f * pw, ay2 = pcy + 0.5f * ph;
        float area_a = (ax2 - ax1) * (ay2 - ay1);

        float cv[NT];
        #pragma unroll
        for (int t = 0; t < NT; ++t) {
            float tcx = tgt_s[t][0], tcy = tgt_s[t][1], tw = tgt_s[t][2], th = tgt_s[t][3];
            float cost_bbox = fabsf(pcx - tcx) + fabsf(pcy - tcy) + fabsf(pw - tw) + fabsf(ph - th);
            float bx1 = tcx - 0.5f * tw, by1 = tcy - 0.5f * th;
            float bx2 = tcx + 0.5f * tw, by2 = tcy + 0.5f * th;
            float area_b = (bx2 - bx1) * (by2 - by1);
            float ltx = fmaxf(ax1, bx1), lty = fmaxf(ay1, by1);
            float rbx = fminf(ax2, bx2), rby = fminf(ay2, by2);
            float wx = fmaxf(rbx - ltx, 0.0f), wy = fmaxf(rby - lty, 0.0f);
            float inter = wx * wy;
            float uni = area_a + area_b - inter;
            float iou = inter / uni;
            float ex1 = fminf(ax1, bx1), ey1 = fminf(ay1, by1);
            float ex2 = fmaxf(ax2, bx2), ey2 = fmaxf(ay2, by2);
            float ewx = fmaxf(ex2 - ex1, 0.0f), ewy = fmaxf(ey2 - ey1, 0.0f);
            float area_e = ewx * ewy;
            float giou = iou - (area_e - uni) / area_e;
            float ct = 5.0f * cost_bbox - 2.0f * giou - p1;
            cv[t] = ct;
            if (has) cost[t][q] = ct;
        }
        if (has) {
            float4* dst = reinterpret_cast<float4*>(Cb + (size_t)q * NT);
            dst[0] = make_float4(cv[0],  cv[1],  cv[2],  cv[3]);
            dst[1] = make_float4(cv[4],  cv[5],  cv[6],  cv[7]);
            dst[2] = make_float4(cv[8],  cv[9],  cv[10], cv[11]);
            dst[3] = make_float4(cv[12], cv[13], cv[14], cv[15]);
        }
    }
    __syncthreads();

    const bool has_cols   = (lane < 60);
    const int  cbase      = has_cols ? lane * CPL : 0;
    const unsigned valid0 = has_cols ? 0x1Fu : 0u;

    double v_reg[CPL];
    int    r4c_reg[CPL];
    int    path_reg[CPL];
    #pragma unroll
    for (int j = 0; j < CPL; ++j) { v_reg[j] = 0.0; r4c_reg[j] = -1; path_reg[j] = -1; }
    double u_reg   = 0.0;     // u[lane] on lanes 0..15
    int    c4r_reg = -1;      // col4row[lane] on lanes 0..15

    // ---- rowmin greedy init (R6-proven: c = 5*lane + j mapping) ----
    int jstar[NT];
    #pragma unroll
    for (int i = 0; i < NT; ++i) {
        const float* crow = &cost[0][0] + i * NQ + cbase;
        float bv = 1e30f; int bj = 0;
        #pragma unroll
        for (int j = 0; j < CPL; ++j) {
            float c = has_cols ? crow[j] : 1e30f;
            if (c < bv) { bv = c; bj = j; }          // ascending j => first-min
        }
        float rv = bv;
        DPP_MINF_ALL
        float m = __int_as_float(__builtin_amdgcn_readlane(__float_as_int(rv), 63));
        unsigned long long tied = __ballot(bv == m);
        int l = __ffsll(tied) - 1;                   // smallest lane = smallest col block
        jstar[i] = __builtin_amdgcn_readlane(cbase + bj, l);
        if (lane == i) u_reg = (double)m;            // exact: f32 min == f64 min of casts
    }

    unsigned unassigned = 0;
    #pragma unroll
    for (int i = 0; i < NT; ++i) {
        int k = jstar[i];
        int owner = k / CPL;
        int slot  = k - owner * CPL;
        int rk    = __builtin_amdgcn_readlane(sel5(r4c_reg, slot), owner);
        if (rk == -1) {
            bool me = (lane == owner);
            r4c_reg[0] = (me && slot == 0) ? i : r4c_reg[0];
            r4c_reg[1] = (me && slot == 1) ? i : r4c_reg[1];
            r4c_reg[2] = (me && slot == 2) ? i : r4c_reg[2];
            r4c_reg[3] = (me && slot == 3) ? i : r4c_reg[3];
            r4c_reg[4] = (me && slot == 4) ? i : r4c_reg[4];
            c4r_reg    = (lane == i) ? k : c4r_reg;
        } else {
            unassigned |= (1u << i);
        }
    }

    // ---- exact f64 Dijkstra augmentation for conflicted rows (R5/R6 body) ----
    for (int cur_row = 0; cur_row < NT; ++cur_row) {
        if (!((unassigned >> cur_row) & 1u)) continue;

        double minv_reg[CPL];
        #pragma unroll
        for (int j = 0; j < CPL; ++j) { minv_reg[j] = 1e300; path_reg[j] = -1; }
        unsigned rem = valid0;

        double shortest = 0.0;
        int i = cur_row;
        int sink = -1;

        for (int guard = 0; guard <= NT && sink < 0; ++guard) {
            const double ui = readlane_d(u_reg, i);

            const float* crow = &cost[0][0] + i * NQ + cbase;
            float cf[CPL];
            #pragma unroll
            for (int j = 0; j < CPL; ++j) cf[j] = crow[j];

            double bestv = 1e300;
            int    bj    = 0;
            #pragma unroll
            for (int j = 0; j < CPL; ++j) {
                unsigned bit = 1u << j;
                if (rem & bit) {
                    // numpy order: ((shortest + cost) - u) - v
                    double r = ((shortest + (double)cf[j]) - ui) - v_reg[j];
                    if (r < minv_reg[j]) { minv_reg[j] = r; path_reg[j] = i; }
                }
                double cv = (rem & bit) ? minv_reg[j] : 1e300;
                if (cv < bestv) { bestv = cv; bj = j; }
            }
            int bestc = cbase + bj;

            DPP_MIN_ALL

            const double m = readlane_d(bestv, 63);
            unsigned long long tied = __ballot(bestv == m);
            if (tied == 0ull) break;            // NaN guard; never on valid data
            int l = __ffsll(tied) - 1;
            int k = __builtin_amdgcn_readlane(bestc, l);
            shortest = m;

            int owner = k / CPL;
            int slot  = k - owner * CPL;
            if (lane == owner) rem &= ~(1u << slot);

            int rk = __builtin_amdgcn_readlane(sel5(r4c_reg, slot), owner);
            if (rk == -1) sink = k;
            else          i = rk;
        }

        // dual updates for scanned (= popped) columns; single-wave block =>
        // lgkmcnt ordering suffices (no barriers)
        #pragma unroll
        for (int j = 0; j < CPL; ++j) {
            unsigned bit = 1u << j;
            if ((valid0 & bit) && !(rem & bit)) {
                double d = shortest - minv_reg[j];
                int r = r4c_reg[j];
                if (r != -1) u_add[r] = d;      // rows distinct, no race
                v_reg[j] -= d;
            }
        }
        if (lane == cur_row) u_reg += shortest;
        if (lane < NT) { u_reg += u_add[lane]; u_add[lane] = 0.0; }

        // augment along path (uniform scalar walk on registers)
        if (sink >= 0) {
            int j = sink;
            #pragma unroll 1
            for (int it = 0; it <= NT; ++it) {
                int ow = j / CPL;
                int sl = j - ow * CPL;
                int ii = __builtin_amdgcn_readlane(sel5(path_reg, sl), ow);
                bool me = (lane == ow);
                r4c_reg[0] = (me && sl == 0) ? ii : r4c_reg[0];
                r4c_reg[1] = (me && sl == 1) ? ii : r4c_reg[1];
                r4c_reg[2] = (me && sl == 2) ? ii : r4c_reg[2];
                r4c_reg[3] = (me && sl == 3) ? ii : r4c_reg[3];
                r4c_reg[4] = (me && sl == 4) ? ii : r4c_reg[4];
                int tmp = __builtin_amdgcn_readlane(c4r_reg, ii);
                c4r_reg = (lane == ii) ? j : c4r_reg;
                j = tmp;
                if (ii == cur_row) break;
            }
        }
    }

    // ---- outputs: order = argsort(col4row) via rank (values distinct) ----
    int myval = c4r_reg;
    int rank = 0;
    #pragma unroll
    for (int s = 0; s < NT; ++s) {
        int vs = __builtin_amdgcn_readlane(c4r_reg, s);
        rank += (vs < myval) ? 1 : 0;
    }
    if (lane < NT) {
        rows_out[b * NT + rank] = (float)myval;
        cols_out[b * NT + rank] = (float)lane;
    }
}

extern "C" void kernel_launch(void* const* d_in, const int* in_sizes, int n_in,
                              void* d_out, int out_size, void* d_ws, size_t ws_size,
                              hipStream_t stream) {
    const float* pred_boxes = (const float*)d_in[1];
    const float* logits_b   = (const float*)d_in[2];
    const float* tgt_boxes  = (const float*)d_in[3];

    float* C    = (float*)d_out;                   // [BS,NQ,NT]
    float* rows = C + (size_t)BS * NQ * NT;        // [BS,NT]
    float* cols = rows + (size_t)BS * NT;          // [BS,NT]

    lsa_fused<<<BS, 64, 0, stream>>>(pred_boxes, logits_b, tgt_boxes, C, rows, cols);
}

// Round 11
// 21.711 us; speedup vs baseline: 1.3786x; 1.3700x over previous
//
#include <hip/hip_runtime.h>
#include <hip/hip_bf16.h>
#include <math.h>

#define BS 128
#define NQ 300
#define NT 16
#define CPL 5   // columns per lane: 300 = 60 lanes * 5 cols, lanes 60..63 idle

union DI { double d; int i[2]; };

// f64 value-only min reduce step via DPP (VALU latency, no index carry)
#define DPP_MIN_STEP(CTRL)                                                    \
    {                                                                         \
        DI a_; a_.d = bestv;                                                  \
        DI p_;                                                                \
        p_.i[0] = __builtin_amdgcn_update_dpp(a_.i[0], a_.i[0], CTRL, 0xF, 0xF, false); \
        p_.i[1] = __builtin_amdgcn_update_dpp(a_.i[1], a_.i[1], CTRL, 0xF, 0xF, false); \
        bestv = fmin(bestv, p_.d);                                            \
    }
#define DPP_MIN_ALL  DPP_MIN_STEP(0x111) DPP_MIN_STEP(0x112) DPP_MIN_STEP(0x114) \
                     DPP_MIN_STEP(0x118) DPP_MIN_STEP(0x142) DPP_MIN_STEP(0x143)

// f32 value-only min reduce step via DPP (operates on local var `rv`)
#define DPP_MINF_STEP(CTRL)                                                   \
    {                                                                         \
        int p_ = __builtin_amdgcn_update_dpp(__float_as_int(rv), __float_as_int(rv), CTRL, 0xF, 0xF, false); \
        rv = fminf(rv, __int_as_float(p_));                                   \
    }
#define DPP_MINF_ALL DPP_MINF_STEP(0x111) DPP_MINF_STEP(0x112) DPP_MINF_STEP(0x114) \
                     DPP_MINF_STEP(0x118) DPP_MINF_STEP(0x142) DPP_MINF_STEP(0x143)

__device__ __forceinline__ double readlane_d(double x, int lane) {
    DI a; a.d = x;
    DI r;
    r.i[0] = __builtin_amdgcn_readlane(a.i[0], lane);
    r.i[1] = __builtin_amdgcn_readlane(a.i[1], lane);
    return r.d;
}

__device__ __forceinline__ int sel5(const int* a, int slot) {
    int r = a[0];
    r = (slot == 1) ? a[1] : r;
    r = (slot == 2) ? a[2] : r;
    r = (slot == 3) ? a[3] : r;
    r = (slot == 4) ? a[4] : r;
    return r;
}

// ---------------------------------------------------------------------------
// One 256-thread block (4 waves) per batch:
//   waves 0-3: cost compute (bit-identical f32 expression) -> C + LDS tile
//   wave 0 only: R6-proven greedy rowmin init + exact f64 Dijkstra fallback
//               (barrier-free single-wave section, proven in R10)
// row4col lookups for uniform k use ballot on the col4row registers
// (injective map; lanes >= NT hold -1).
// ---------------------------------------------------------------------------
__global__ __launch_bounds__(256) void lsa_fused(const float* __restrict__ pred_boxes, // [BS,NQ,4]
                                                 const float* __restrict__ logits_b,   // [BS,NQ,2]
                                                 const float* __restrict__ tgt_boxes,  // [BS,NT,5]
                                                 float* __restrict__ C,                // [BS,NQ,NT]
                                                 float* __restrict__ rows_out,         // [BS,NT]
                                                 float* __restrict__ cols_out)         // [BS,NT]
{
    const int b   = blockIdx.x;
    const int tid = threadIdx.x;

    __shared__ float  cost[NT][NQ];          // cost[t][q]
    __shared__ double u_add[NT];
    __shared__ __align__(16) float tgt_s[NT][4];

    if (tid < 64) {
        int t = tid >> 2, d = tid & 3;
        tgt_s[t][d] = tgt_boxes[((size_t)b * NT + t) * 5 + 1 + d];
    }
    if (tid < NT) u_add[tid] = 0.0;
    __syncthreads();

    // ---- parallel cost compute (4 waves): q = tid, tid+256 ----
    float* Cb = C + (size_t)b * NQ * NT;
    for (int q = tid; q < NQ; q += 256) {
        float4 pb = *reinterpret_cast<const float4*>(pred_boxes + ((size_t)b * NQ + q) * 4);
        float2 lg = *reinterpret_cast<const float2*>(logits_b  + ((size_t)b * NQ + q) * 2);
        float pcx = pb.x, pcy = pb.y, pw = pb.z, ph = pb.w;
        float mm = fmaxf(lg.x, lg.y);
        float e0 = expf(lg.x - mm), e1 = expf(lg.y - mm);
        float p1 = e1 / (e0 + e1);
        float ax1 = pcx - 0.5f * pw, ay1 = pcy - 0.5f * ph;
        float ax2 = pcx + 0.5f * pw, ay2 = pcy + 0.5f * ph;
        float area_a = (ax2 - ax1) * (ay2 - ay1);

        float cv[NT];
        #pragma unroll
        for (int t = 0; t < NT; ++t) {
            float tcx = tgt_s[t][0], tcy = tgt_s[t][1], tw = tgt_s[t][2], th = tgt_s[t][3];
            float cost_bbox = fabsf(pcx - tcx) + fabsf(pcy - tcy) + fabsf(pw - tw) + fabsf(ph - th);
            float bx1 = tcx - 0.5f * tw, by1 = tcy - 0.5f * th;
            float bx2 = tcx + 0.5f * tw, by2 = tcy + 0.5f * th;
            float area_b = (bx2 - bx1) * (by2 - by1);
            float ltx = fmaxf(ax1, bx1), lty = fmaxf(ay1, by1);
            float rbx = fminf(ax2, bx2), rby = fminf(ay2, by2);
            float wx = fmaxf(rbx - ltx, 0.0f), wy = fmaxf(rby - lty, 0.0f);
            float inter = wx * wy;
            float uni = area_a + area_b - inter;
            float iou = inter / uni;
            float ex1 = fminf(ax1, bx1), ey1 = fminf(ay1, by1);
            float ex2 = fmaxf(ax2, bx2), ey2 = fmaxf(ay2, by2);
            float ewx = fmaxf(ex2 - ex1, 0.0f), ewy = fmaxf(ey2 - ey1, 0.0f);
            float area_e = ewx * ewy;
            float giou = iou - (area_e - uni) / area_e;
            float ct = 5.0f * cost_bbox - 2.0f * giou - p1;
            cv[t] = ct;
            cost[t][q] = ct;
        }
        float4* dst = reinterpret_cast<float4*>(Cb + (size_t)q * NT);
        dst[0] = make_float4(cv[0],  cv[1],  cv[2],  cv[3]);
        dst[1] = make_float4(cv[4],  cv[5],  cv[6],  cv[7]);
        dst[2] = make_float4(cv[8],  cv[9],  cv[10], cv[11]);
        dst[3] = make_float4(cv[12], cv[13], cv[14], cv[15]);
    }
    __syncthreads();
    if (tid >= 64) return;               // waves 1-3 done; wave 0 continues

    const int  lane       = tid;
    const bool has_cols   = (lane < 60);
    const int  cbase      = has_cols ? lane * CPL : 0;
    const unsigned valid0 = has_cols ? 0x1Fu : 0u;

    double v_reg[CPL];
    int    r4c_reg[CPL];
    int    path_reg[CPL];
    #pragma unroll
    for (int j = 0; j < CPL; ++j) { v_reg[j] = 0.0; r4c_reg[j] = -1; path_reg[j] = -1; }
    double u_reg   = 0.0;     // u[lane] on lanes 0..15
    int    c4r_reg = -1;      // col4row[lane] on lanes 0..15 (-1 elsewhere, never set)

    // ---- rowmin greedy init (R6-proven trajectory: == reference when free) ----
    int jstar[NT];
    #pragma unroll
    for (int i = 0; i < NT; ++i) {
        const float* crow = &cost[0][0] + i * NQ + cbase;
        float bv = 1e30f; int bj = 0;
        #pragma unroll
        for (int j = 0; j < CPL; ++j) {
            float c = has_cols ? crow[j] : 1e30f;
            if (c < bv) { bv = c; bj = j; }          // ascending j => first-min
        }
        float rv = bv;
        DPP_MINF_ALL
        float m = __int_as_float(__builtin_amdgcn_readlane(__float_as_int(rv), 63));
        unsigned long long tied = __ballot(bv == m);
        int l = __ffsll(tied) - 1;                   // smallest lane = smallest col block
        jstar[i] = __builtin_amdgcn_readlane(cbase + bj, l);
        if (lane == i) u_reg = (double)m;            // exact: f32 min == f64 min of casts
    }

    unsigned unassigned = 0;
    #pragma unroll
    for (int i = 0; i < NT; ++i) {
        int k = jstar[i];
        // row4col[k] via inverse lookup on col4row (injective): ballot + ffs
        unsigned long long mmk = __ballot(c4r_reg == k);
        int rk = mmk ? (__ffsll(mmk) - 1) : -1;
        if (rk == -1) {
            int owner = k / CPL;
            int slot  = k - owner * CPL;
            bool me = (lane == owner);
            r4c_reg[0] = (me && slot == 0) ? i : r4c_reg[0];
            r4c_reg[1] = (me && slot == 1) ? i : r4c_reg[1];
            r4c_reg[2] = (me && slot == 2) ? i : r4c_reg[2];
            r4c_reg[3] = (me && slot == 3) ? i : r4c_reg[3];
            r4c_reg[4] = (me && slot == 4) ? i : r4c_reg[4];
            c4r_reg    = (lane == i) ? k : c4r_reg;
        } else {
            unassigned |= (1u << i);
        }
    }

    // ---- exact f64 Dijkstra augmentation for conflicted rows (R5/R6 body,
    //      barrier-free per R10) ----
    for (int cur_row = 0; cur_row < NT; ++cur_row) {
        if (!((unassigned >> cur_row) & 1u)) continue;

        double minv_reg[CPL];
        #pragma unroll
        for (int j = 0; j < CPL; ++j) { minv_reg[j] = 1e300; path_reg[j] = -1; }
        unsigned rem = valid0;

        double shortest = 0.0;
        int i = cur_row;
        int sink = -1;

        for (int guard = 0; guard <= NT && sink < 0; ++guard) {
            const double ui = readlane_d(u_reg, i);

            const float* crow = &cost[0][0] + i * NQ + cbase;
            float cf[CPL];
            #pragma unroll
            for (int j = 0; j < CPL; ++j) cf[j] = crow[j];

            double bestv = 1e300;
            int    bj    = 0;
            #pragma unroll
            for (int j = 0; j < CPL; ++j) {
                unsigned bit = 1u << j;
                if (rem & bit) {
                    // numpy order: ((shortest + cost) - u) - v
                    double r = ((shortest + (double)cf[j]) - ui) - v_reg[j];
                    if (r < minv_reg[j]) { minv_reg[j] = r; path_reg[j] = i; }
                }
                double cv = (rem & bit) ? minv_reg[j] : 1e300;
                if (cv < bestv) { bestv = cv; bj = j; }
            }
            int bestc = cbase + bj;

            DPP_MIN_ALL

            const double m = readlane_d(bestv, 63);
            unsigned long long tied = __ballot(bestv == m);
            if (tied == 0ull) break;            // NaN guard; never on valid data
            int l = __ffsll(tied) - 1;
            int k = __builtin_amdgcn_readlane(bestc, l);
            shortest = m;

            int owner = k / CPL;
            int slot  = k - owner * CPL;
            if (lane == owner) rem &= ~(1u << slot);

            unsigned long long mmk = __ballot(c4r_reg == k);
            int rk = mmk ? (__ffsll(mmk) - 1) : -1;
            if (rk == -1) sink = k;
            else          i = rk;
        }

        // dual updates for scanned (= popped) columns (single-wave, no barrier)
        #pragma unroll
        for (int j = 0; j < CPL; ++j) {
            unsigned bit = 1u << j;
            if ((valid0 & bit) && !(rem & bit)) {
                double d = shortest - minv_reg[j];
                int r = r4c_reg[j];
                if (r != -1) u_add[r] = d;      // rows distinct, no race
                v_reg[j] -= d;
            }
        }
        if (lane == cur_row) u_reg += shortest;
        if (lane < NT) { u_reg += u_add[lane]; u_add[lane] = 0.0; }

        // augment along path (uniform scalar walk on registers)
        if (sink >= 0) {
            int j = sink;
            #pragma unroll 1
            for (int it = 0; it <= NT; ++it) {
                int ow = j / CPL;
                int sl = j - ow * CPL;
                int ii = __builtin_amdgcn_readlane(sel5(path_reg, sl), ow);
                bool me = (lane == ow);
                r4c_reg[0] = (me && sl == 0) ? ii : r4c_reg[0];
                r4c_reg[1] = (me && sl == 1) ? ii : r4c_reg[1];
                r4c_reg[2] = (me && sl == 2) ? ii : r4c_reg[2];
                r4c_reg[3] = (me && sl == 3) ? ii : r4c_reg[3];
                r4c_reg[4] = (me && sl == 4) ? ii : r4c_reg[4];
                int tmp = __builtin_amdgcn_readlane(c4r_reg, ii);
                c4r_reg = (lane == ii) ? j : c4r_reg;
                j = tmp;
                if (ii == cur_row) break;
            }
        }
    }

    // ---- outputs: order = argsort(col4row) via rank (values distinct) ----
    int myval = c4r_reg;
    int rank = 0;
    #pragma unroll
    for (int s = 0; s < NT; ++s) {
        int vs = __builtin_amdgcn_readlane(c4r_reg, s);
        rank += (vs < myval) ? 1 : 0;
    }
    if (lane < NT) {
        rows_out[b * NT + rank] = (float)myval;
        cols_out[b * NT + rank] = (float)lane;
    }
}

extern "C" void kernel_launch(void* const* d_in, const int* in_sizes, int n_in,
                              void* d_out, int out_size, void* d_ws, size_t ws_size,
                              hipStream_t stream) {
    const float* pred_boxes = (const float*)d_in[1];
    const float* logits_b   = (const float*)d_in[2];
    const float* tgt_boxes  = (const float*)d_in[3];

    float* C    = (float*)d_out;                   // [BS,NQ,NT]
    float* rows = C + (size_t)BS * NQ * NT;        // [BS,NT]
    float* cols = rows + (size_t)BS * NT;          // [BS,NT]

    lsa_fused<<<BS, 256, 0, stream>>>(pred_boxes, logits_b, tgt_boxes, C, rows, cols);
}